// Round 3
// baseline (221.970 us; speedup 1.0000x reference)
//
#include <hip/hip_runtime.h>
#include <hip/hip_bf16.h>
#include <math.h>

// Problem: B=2, T=2048, D_MODEL=1024, H=16, HD=64.
// I/O is FP32 (per reference dtypes); internal compute bf16 MFMA.
// Pipeline: cvt weights -> rmsnorm(f32->bf16) -> qkv gemm (bf16) -> rope(in-place)
//   + V transpose -> flash attn (out in-place over Q slot) -> out gemm (bf16 A/B,
//   f32 residual, f32 out).
// Workspace (40MB): [qkv 12M][xn/vt 4M][wqkvb 3M][woutb 1M] bf16 elems.

typedef __bf16 bf16;
typedef __bf16 bf16x8 __attribute__((ext_vector_type(8)));
typedef __bf16 bf16x4 __attribute__((ext_vector_type(4)));
typedef float  f32x4  __attribute__((ext_vector_type(4)));

// async global->LDS, 16B per lane; LDS dest is wave-uniform base + lane*16
#define GLOAD16(g, l) __builtin_amdgcn_global_load_lds( \
    (const __attribute__((address_space(1))) void*)(g),  \
    (__attribute__((address_space(3))) void*)(l), 16, 0, 0)

__device__ __forceinline__ unsigned pk2(float a, float b) {
  unsigned short lo = __builtin_bit_cast(unsigned short, (bf16)a);
  unsigned short hi = __builtin_bit_cast(unsigned short, (bf16)b);
  return (unsigned)lo | ((unsigned)hi << 16);
}

// ---------------- fp32 -> bf16 conversion (weights) ----------------
__global__ __launch_bounds__(256) void k_cvt(const float* __restrict__ src,
    bf16* __restrict__ dst, int n) {
  int i = (blockIdx.x * 256 + threadIdx.x) * 8;
  if (i >= n) return;
  float4 a = *(const float4*)(src + i);
  float4 b = *(const float4*)(src + i + 4);
  bf16x8 o;
  o[0] = (bf16)a.x; o[1] = (bf16)a.y; o[2] = (bf16)a.z; o[3] = (bf16)a.w;
  o[4] = (bf16)b.x; o[5] = (bf16)b.y; o[6] = (bf16)b.z; o[7] = (bf16)b.w;
  *(bf16x8*)(dst + i) = o;
}

// ---------------- RMSNorm: x[4096][1024] f32 -> xn bf16 ----------------
__global__ __launch_bounds__(256) void k_rmsnorm(const float* __restrict__ x,
    const float* __restrict__ w, bf16* __restrict__ xn) {
  const int row = blockIdx.x, tid = threadIdx.x;
  float4 v = *(const float4*)(x + (size_t)row * 1024 + tid * 4);
  float ss = v.x * v.x + v.y * v.y + v.z * v.z + v.w * v.w;
  for (int m = 32; m >= 1; m >>= 1) ss += __shfl_xor(ss, m);
  __shared__ float red[4];
  if ((tid & 63) == 0) red[tid >> 6] = ss;
  __syncthreads();
  float ms = (red[0] + red[1] + red[2] + red[3]) * (1.f / 1024.f);
  float r = rsqrtf(ms + 1e-5f);
  float4 wv = *(const float4*)(w + tid * 4);
  bf16x4 o;
  o[0] = (bf16)(v.x * r * wv.x); o[1] = (bf16)(v.y * r * wv.y);
  o[2] = (bf16)(v.z * r * wv.z); o[3] = (bf16)(v.w * r * wv.w);
  *(bf16x4*)(xn + (size_t)row * 1024 + tid * 4) = o;
}

// ---------------- GEMM: C[M][N] = A[M][K](lda) @ B[N][K]^T, bf16 inputs ----------------
// RESID=0: C bf16.  RESID=1: C fp32, plus fp32 residual R.
// 128x128 tile, BK=64, 4 waves 2x2, 16x16x32 bf16 MFMA, xor-swizzled LDS.
template<int RESID>
__global__ __launch_bounds__(256, 2) void k_gemm_bt(const bf16* __restrict__ A,
    const bf16* __restrict__ B, const float* __restrict__ R, void* __restrict__ Cv,
    int M, int N, int K, int lda) {
  const int tid = threadIdx.x;
  const int lane = tid & 63, L15 = lane & 15, quad = lane >> 4;
  const int wave = tid >> 6, wr = wave >> 1, wc = wave & 1;
  const int n0 = blockIdx.x * 128, m0 = blockIdx.y * 128;
  __shared__ __align__(16) bf16 smem[17408];   // sA(8192)+sB(8192); epilogue reuses as 128x136
  bf16* sA = smem; bf16* sB = smem + 8192;
  f32x4 acc[4][4];
  const f32x4 z = {0.f, 0.f, 0.f, 0.f};
  for (int i = 0; i < 4; i++) for (int j = 0; j < 4; j++) acc[i][j] = z;

  for (int k0 = 0; k0 < K; k0 += 64) {
    const bf16* Ab = A + (size_t)m0 * lda + k0;
    const bf16* Bb = B + (size_t)n0 * K + k0;
    for (int p = 0; p < 4; p++) {       // 128 rows x 8 chunks(16B) per buffer
      int s = p * 256 + tid, r = s >> 3, c8 = (s & 7) ^ (r & 7);
      GLOAD16(Ab + (size_t)r * lda + c8 * 8, sA + s * 8);
      GLOAD16(Bb + (size_t)r * K + c8 * 8, sB + s * 8);
    }
    __syncthreads();
    for (int kk = 0; kk < 2; kk++) {
      bf16x8 af[4], bfv[4];
      for (int i = 0; i < 4; i++) {
        int ra = wr * 64 + i * 16 + L15;
        af[i] = *(const bf16x8*)(sA + ra * 64 + (((kk * 4 + quad) ^ (ra & 7)) * 8));
        int rb = wc * 64 + i * 16 + L15;
        bfv[i] = *(const bf16x8*)(sB + rb * 64 + (((kk * 4 + quad) ^ (rb & 7)) * 8));
      }
      for (int mt = 0; mt < 4; mt++)
        for (int nt = 0; nt < 4; nt++)
          acc[mt][nt] = __builtin_amdgcn_mfma_f32_16x16x32_bf16(af[mt], bfv[nt], acc[mt][nt], 0, 0, 0);
    }
    __syncthreads();
  }
  // epilogue: LDS transpose (bf16) for coalesced stores
  bf16* sC = smem;   // [128][136]
  for (int mt = 0; mt < 4; mt++) for (int nt = 0; nt < 4; nt++) {
    int r = wr * 64 + mt * 16 + quad * 4, c = wc * 64 + nt * 16 + L15;
    f32x4 v = acc[mt][nt];
    for (int g = 0; g < 4; g++) sC[(r + g) * 136 + c] = (bf16)v[g];
  }
  __syncthreads();
  const int rr = tid >> 1, sg = (tid & 1) * 64;
  const size_t row = (size_t)m0 + rr;
  const bf16* src = sC + rr * 136 + sg;
  if (RESID) {   // fp32 out + fp32 residual
    float* Cf = (float*)Cv;
    const float* rs = R + row * N + n0 + sg;
    float* dst = Cf + row * N + n0 + sg;
    for (int i = 0; i < 16; i++) {
      bf16x4 u = *(const bf16x4*)(src + i * 4);
      float4 rv = *(const float4*)(rs + i * 4);
      float4 o;
      o.x = (float)u[0] + rv.x; o.y = (float)u[1] + rv.y;
      o.z = (float)u[2] + rv.z; o.w = (float)u[3] + rv.w;
      *(float4*)(dst + i * 4) = o;
    }
  } else {       // bf16 out
    bf16* Cb = (bf16*)Cv;
    bf16* dst = Cb + row * N + n0 + sg;
    for (int i = 0; i < 8; i++)
      *(bf16x8*)(dst + i * 8) = *(const bf16x8*)(src + i * 8);
  }
}

// ---------------- RoPE in-place on qkv Q/K slots; V transposed to vt[bh][d][t] ----------------
__global__ __launch_bounds__(256) void k_rope(bf16* __restrict__ qkv,
    bf16* __restrict__ vt) {
  const int blk = blockIdx.x;
  const int tt = blk & 31, h = (blk >> 5) & 15, b = blk >> 9;
  const int tid = threadIdx.x;
  const int bh = b * 16 + h;
  { // phase A: rope q,k in place. 64 t x 4 d-chunk pairs (d, d+32)
    const int tl = tid >> 2, dp = (tid & 3) * 8;
    const int tg = tt * 64 + tl;
    bf16* base = qkv + (size_t)(b * 2048 + tg) * 3072 + h * 64;
    bf16x8 qlo = *(const bf16x8*)(base + dp);
    bf16x8 qhi = *(const bf16x8*)(base + dp + 32);
    bf16x8 klo = *(const bf16x8*)(base + 1024 + dp);
    bf16x8 khi = *(const bf16x8*)(base + 1024 + dp + 32);
    bf16x8 oql, oqh, okl, okh;
    for (int j = 0; j < 8; j++) {
      // inv_freq = 10000^(-(dp+j)/32) = 2^(-(dp+j)*log2(10000)/32)
      float invf = exp2f(-0.41524101186f * (float)(dp + j));
      float th = (float)tg * invf;
      float sn, cs;
      sincosf(th, &sn, &cs);   // accurate range reduction (theta up to 2047 rad)
      float a0 = (float)qlo[j], a1 = (float)qhi[j];
      float b0 = (float)klo[j], b1 = (float)khi[j];
      oql[j] = (bf16)(a0 * cs - a1 * sn);
      oqh[j] = (bf16)(a1 * cs + a0 * sn);
      okl[j] = (bf16)(b0 * cs - b1 * sn);
      okh[j] = (bf16)(b1 * cs + b0 * sn);
    }
    *(bf16x8*)(base + dp) = oql; *(bf16x8*)(base + dp + 32) = oqh;
    *(bf16x8*)(base + 1024 + dp) = okl; *(bf16x8*)(base + 1024 + dp + 32) = okh;
  }
  // phase B: transpose V tile 64t x 64d -> vt[bh][d][t]
  __shared__ __align__(16) bf16 sT[64 * 72];
  for (int p = 0; p < 2; p++) {
    int s = p * 256 + tid, tl = s >> 3, c = s & 7;
    const bf16* vsrc = qkv + (size_t)(b * 2048 + tt * 64 + tl) * 3072 + 2048 + h * 64 + c * 8;
    *(bf16x8*)(sT + tl * 72 + c * 8) = *(const bf16x8*)vsrc;
  }
  __syncthreads();
  for (int p = 0; p < 2; p++) {
    int s = p * 256 + tid, d = s >> 3, tc = s & 7;
    bf16x8 v;
    for (int j = 0; j < 8; j++) v[j] = sT[(tc * 8 + j) * 72 + d];
    *(bf16x8*)(vt + (size_t)bh * 131072 + (size_t)d * 2048 + tt * 64 + tc * 8) = v;
  }
}

// ---------------- Flash attention (bidirectional), S^T formulation ----------------
// Q,K from qkv (row stride 3072); V from vt[bh][d][t]; output in place over Q slot.
// S^T = K*Q^T  (C-layout: row=kv, col=q -> regs are 4 consecutive kv => b64 P writes)
// O^T = V^T*P^T (a-frag from vt LDS, b-frag = contiguous rows of P[q][kv])
__global__ __launch_bounds__(256, 2) void k_attn(bf16* __restrict__ qkv,
    const bf16* __restrict__ vt) {
  const int tid = threadIdx.x;
  const int lane = tid & 63, L15 = lane & 15, quad = lane >> 4;
  const int wave = tid >> 6;
  const int bh = blockIdx.y, b = bh >> 4, h = bh & 15;
  const int q0 = blockIdx.x * 128;
  const bf16* Q  = qkv + (size_t)b * 2048 * 3072 + h * 64;           // + t*3072
  const bf16* Kg = qkv + (size_t)b * 2048 * 3072 + 1024 + h * 64;    // + t*3072
  const bf16* Vg = vt + (size_t)bh * 131072;                         // [d][2048]
  __shared__ __align__(16) bf16 sK[8192];     // [128 kv][64 d] swizzled
  __shared__ __align__(16) bf16 sV[8192];     // [64 d][128 kv] swizzled
  __shared__ __align__(16) bf16 sP[17408];    // [128 q][136 kv] (stride 272B: 16B-aligned rows)

  bf16x8 qf[2][2];  // b-operand frags: Q[q][d], once per block
  for (int qt = 0; qt < 2; qt++) for (int kk = 0; kk < 2; kk++) {
    int rq = q0 + wave * 32 + qt * 16 + L15;
    qf[qt][kk] = *(const bf16x8*)(Q + (size_t)rq * 3072 + kk * 32 + quad * 8);
  }
  f32x4 o[4][2];
  const f32x4 z = {0.f, 0.f, 0.f, 0.f};
  for (int i = 0; i < 4; i++) for (int j = 0; j < 2; j++) o[i][j] = z;
  float mrun[2] = {-1e30f, -1e30f};
  float lrun[2] = {0.f, 0.f};
  const float c2 = 0.125f;   // 1/sqrt(64), folded into exp

  for (int kv0 = 0; kv0 < 2048; kv0 += 128) {
    __syncthreads();   // previous iter's LDS reads complete
    const bf16* Kb = Kg + (size_t)kv0 * 3072;
    for (int p = 0; p < 4; p++) {   // K: 128 rows x 8 chunks
      int s = p * 256 + tid, r = s >> 3, c8 = (s & 7) ^ (r & 7);
      GLOAD16(Kb + (size_t)r * 3072 + c8 * 8, sK + s * 8);
    }
    for (int p = 0; p < 4; p++) {   // Vt: 64 rows x 16 chunks (xor low-3 bits)
      int s = p * 256 + tid, r = s >> 4, cl = s & 15;
      int c8 = (cl & 8) | ((cl ^ (r & 7)) & 7);
      GLOAD16(Vg + (size_t)r * 2048 + kv0 + c8 * 8, sV + s * 8);
    }
    __syncthreads();
    f32x4 st[8][2];
    for (int i = 0; i < 8; i++) for (int j = 0; j < 2; j++) st[i][j] = z;
    for (int kk = 0; kk < 2; kk++) {
      bf16x8 kf[8];
      for (int kvt = 0; kvt < 8; kvt++) {
        int rk = kvt * 16 + L15;
        kf[kvt] = *(const bf16x8*)(sK + rk * 64 + (((kk * 4 + quad) ^ (rk & 7)) * 8));
      }
      for (int kvt = 0; kvt < 8; kvt++)
        for (int qt = 0; qt < 2; qt++)
          st[kvt][qt] = __builtin_amdgcn_mfma_f32_16x16x32_bf16(kf[kvt], qf[qt][kk], st[kvt][qt], 0, 0, 0);
    }
    // online softmax per q (q = col => per-lane scalar stats, 2 shuffles)
    for (int qt = 0; qt < 2; qt++) {
      float m = st[0][qt][0];
      for (int kvt = 0; kvt < 8; kvt++)
        for (int g = 0; g < 4; g++) m = fmaxf(m, st[kvt][qt][g]);
      m = fmaxf(m, __shfl_xor(m, 16));
      m = fmaxf(m, __shfl_xor(m, 32));
      float mnew = fmaxf(mrun[qt], m);
      float alpha = __expf((mrun[qt] - mnew) * c2);
      float mc = mnew * c2;
      float ls = 0.f;
      int rq = wave * 32 + qt * 16 + L15;
      for (int kvt = 0; kvt < 8; kvt++) {
        float p0 = __expf(st[kvt][qt][0] * c2 - mc);
        float p1 = __expf(st[kvt][qt][1] * c2 - mc);
        float p2 = __expf(st[kvt][qt][2] * c2 - mc);
        float p3 = __expf(st[kvt][qt][3] * c2 - mc);
        ls += (p0 + p1) + (p2 + p3);
        uint2 w2; w2.x = pk2(p0, p1); w2.y = pk2(p2, p3);
        *(uint2*)(sP + rq * 136 + kvt * 16 + quad * 4) = w2;   // 4 consecutive kv
      }
      ls += __shfl_xor(ls, 16);
      ls += __shfl_xor(ls, 32);
      lrun[qt] = lrun[qt] * alpha + ls;
      mrun[qt] = mnew;
      for (int dt = 0; dt < 4; dt++) o[dt][qt] *= alpha;
    }
    // O^T += V^T @ P^T (wave reads only its own P rows -> no barrier needed)
    for (int kc = 0; kc < 4; kc++) {
      bf16x8 vf[4], pf[2];
      for (int dt = 0; dt < 4; dt++) {
        int rd = dt * 16 + L15;
        int c = kc * 4 + quad;
        int cs = (c & 8) | ((c ^ (rd & 7)) & 7);
        vf[dt] = *(const bf16x8*)(sV + rd * 128 + cs * 8);
      }
      for (int qt = 0; qt < 2; qt++) {
        int rq = wave * 32 + qt * 16 + L15;
        pf[qt] = *(const bf16x8*)(sP + rq * 136 + kc * 32 + quad * 8);
      }
      for (int dt = 0; dt < 4; dt++)
        for (int qt = 0; qt < 2; qt++)
          o[dt][qt] = __builtin_amdgcn_mfma_f32_16x16x32_bf16(vf[dt], pf[qt], o[dt][qt], 0, 0, 0);
    }
  }
  float invl[2] = {1.f / lrun[0], 1.f / lrun[1]};
  __syncthreads();               // sP alias: all waves done with PV reads
  bf16* sO = sP;                 // [128 q][72 d]
  for (int dt = 0; dt < 4; dt++) for (int qt = 0; qt < 2; qt++) {
    f32x4 v = o[dt][qt] * invl[qt];
    int ql = wave * 32 + qt * 16 + L15;
    uint2 w2; w2.x = pk2(v[0], v[1]); w2.y = pk2(v[2], v[3]);
    *(uint2*)(sO + ql * 72 + dt * 16 + quad * 4) = w2;  // regs = consecutive d
  }
  __syncthreads();
  const int rr = tid >> 1, sg = (tid & 1) * 32;
  const bf16* src = sO + rr * 72 + sg;
  bf16* dst = qkv + (size_t)(b * 2048 + q0 + rr) * 3072 + h * 64 + sg;  // Q slot, in place
  for (int i = 0; i < 4; i++)
    *(bf16x8*)(dst + i * 8) = *(const bf16x8*)(src + i * 8);
}

extern "C" void kernel_launch(void* const* d_in, const int* in_sizes, int n_in,
                              void* d_out, int out_size, void* d_ws, size_t ws_size,
                              hipStream_t stream) {
  (void)in_sizes; (void)n_in; (void)out_size;
  const float* x     = (const float*)d_in[0];   // fp32 per reference dtypes
  const float* normw = (const float*)d_in[1];
  const float* wqkv  = (const float*)d_in[2];
  const float* wout  = (const float*)d_in[3];
  float* out = (float*)d_out;
  bf16* ws  = (bf16*)d_ws;
  // 40MB workspace: [qkv 12M][xn/vt 4M][wqkvb 3M][woutb 1M] bf16 elems
  const size_t NQKV = (size_t)4096 * 3072, NXN = (size_t)4096 * 1024;
  const size_t NWQ = (size_t)3072 * 1024, NWO = (size_t)1024 * 1024;
  const size_t need = (NQKV + NXN + NWQ + NWO) * sizeof(bf16);
  if (ws_size < need) return;   // debug signal: absmax ~= 4.97 => ws too small
  bf16* qkv    = ws;
  bf16* xn     = qkv + NQKV;    // reused as vt after qkv gemm consumes xn
  bf16* vtp    = xn;
  bf16* wqkvb  = xn + NXN;
  bf16* woutb  = wqkvb + NWQ;
  k_cvt<<<(int)(NWQ / 8 / 256), 256, 0, stream>>>(wqkv, wqkvb, (int)NWQ);
  k_cvt<<<(int)(NWO / 8 / 256), 256, 0, stream>>>(wout, woutb, (int)NWO);
  k_rmsnorm<<<4096, 256, 0, stream>>>(x, normw, xn);
  k_gemm_bt<0><<<dim3(24, 32), 256, 0, stream>>>(xn, wqkvb, nullptr, qkv, 4096, 3072, 1024, 1024);
  k_rope<<<1024, 256, 0, stream>>>(qkv, vtp);
  k_attn<<<dim3(16, 32), 256, 0, stream>>>(qkv, vtp);
  k_gemm_bt<1><<<dim3(8, 32), 256, 0, stream>>>(qkv, woutb, x, out, 4096, 1024, 1024, 3072);
}